// Round 2
// baseline (129.352 us; speedup 1.0000x reference)
//
#include <hip/hip_runtime.h>
#include <math.h>

#define TS   32
#define PT   36
#define NPIX 1024
#define DF   72      // real feature dim
#define KP   96      // padded K: 3 MFMA k-steps of 32
#define IMH  320
#define IMW  320
#define NTW  10
#define NTILE 100

// ws layout offsets unchanged from proven R3..R11
#define F_UNITS_PER_TILE 12288           // 64 rt * 3 ks * 4 c * 16 rows
#define FHI_BYTES (NTILE * F_UNITS_PER_TILE * 16)   // 19,660,800
#define SQ_OFF    (2 * FHI_BYTES)                   // 39,321,600

#define K2LOG2E 2.0813689810056077f      // (log2 e)^2: exp(-sqrt(x)) = exp2(-sqrt(K2*x))

typedef __attribute__((ext_vector_type(8))) short bf16x8;   // MFMA A/B frag
typedef __attribute__((ext_vector_type(8))) unsigned short u16x8;
typedef __attribute__((ext_vector_type(4))) float f32x4;    // MFMA C/D
typedef __attribute__((ext_vector_type(4))) __fp16 f16x4;   // 16x16x16 f16 A/B frag
typedef __attribute__((ext_vector_type(2))) __fp16 f16x2;

// ---------------- kernel A: feature build (RNE bf16) + sqf ----------------
// R12 change: Sq stored pre-scaled by K2LOG2E (gemm consumes it directly).
__global__ __launch_bounds__(256)
void nlm_feat_kernel(const float* __restrict__ img,
                     u16x8* __restrict__ Fhi, float* __restrict__ Sq)
{
    __shared__ float Ploc[3][6][36];   // padded rows [2p, 2p+6) of the tile
    __shared__ int   ofsl[KP];
    const int tid  = threadIdx.x;
    const int part = blockIdx.x;    // 0..15
    const int tile = blockIdx.y;
    const int by   = (tile / NTW) * TS;
    const int bx   = (tile % NTW) * TS;
    const float* Pf = &Ploc[0][0][0];

    for (int idx = tid; idx < 3 * 6 * 36; idx += 256) {
        int c   = idx / 216;
        int rem = idx - c * 216;
        int yl  = rem / 36;
        int x   = rem - yl * 36;
        int y   = 2 * part + yl;
        int iy  = min(max(y - 2, 0), TS - 1);
        int ix  = min(max(x - 2, 0), TS - 1);
        Ploc[c][yl][x] = img[(c * IMH + by + iy) * IMW + bx + ix];
    }
    if (tid < KP) {
        int k = tid, v = 0;
        if (k < DF) {
            int c = k / 24, o = k - c * 24;
            int kk = o + (o >= 12);
            int i = kk / 5, j = kk - (kk / 5) * 5;
            v = c * 216 + i * 36 + j;
        }
        ofsl[k] = v;
    }
    __syncthreads();

    if (tid < 64) {
        int m  = part * 64 + tid;
        int my = m >> 5, mx = m & 31;
        int ly0 = my - 2 * part;
        float s = 0.f;
        #pragma unroll
        for (int k = 0; k < 25; ++k) {
            if (k == 12) continue;
            int i = k / 5, j = k - (k / 5) * 5;
            float v0 = Ploc[0][ly0 + i][mx + j];
            float v1 = Ploc[1][ly0 + i][mx + j];
            float v2 = Ploc[2][ly0 + i][mx + j];
            s = fmaf(v0, v0, s); s = fmaf(v1, v1, s); s = fmaf(v2, v2, s);
        }
        Sq[tile * NPIX + m] = s * K2LOG2E;   // pre-scaled
    }

    #pragma unroll
    for (int q = 0; q < 3; ++q) {
        int u    = part * 768 + q * 256 + tid;
        int row  = u & 15;
        int c4   = (u >> 4) & 3;
        int rks  = u >> 6;
        int ks   = rks - (rks / 3) * 3;
        int rt   = rks / 3;
        int r    = rt * 16 + row;
        int lbase = ((r >> 5) - 2 * part) * 36 + (r & 31);
        u16x8 h;
        #pragma unroll
        for (int j = 0; j < 8; ++j) {
            int k = ks * 32 + c4 * 8 + j;
            unsigned short hs = 0;
            if (k < DF) {
                float f = Pf[lbase + ofsl[k]];
                unsigned int uu = __float_as_uint(f);
                hs = (unsigned short)((uu + 0x7fffu + ((uu >> 16) & 1u)) >> 16);
            }
            h[j] = hs;
        }
        Fhi[tile * F_UNITS_PER_TILE + u] = h;
    }
}

// ---------------- kernel B: Gram MFMA + PV-MFMA accumulation --------------
// R12: swap Gram operands (S^T fragment: row=m, col=n; valid since S symmetric).
// D-fragment layout (row=4q+i, col) == A-layout of mfma_f32_16x16x16f16
// (lane holds A[row=l&15][k=4*(l>>4)+j]) -> densities feed a second MFMA with
// B = [y0,y1,y2,1] (f16 hi + f16 lo residual), no cross-lane movement.
// Removes per-pair {cmp,cndmask,rowsum add,3 oacc fma} + the shuffle storm.
__global__ __launch_bounds__(256)
__attribute__((amdgpu_waves_per_eu(2, 3)))
void nlm_gemm_kernel(const float* __restrict__ img,
                     const bf16x8* __restrict__ Fhi,
                     const float* __restrict__ SqK, float* __restrict__ out)
{
    __shared__ __fp16 Yhi[4][1032];   // pitch 1032: banks 0/4/8/12 across c
    __shared__ __fp16 Ylo[4][1032];
    __shared__ float red[4][2][16][4];  // [wave][t][row][c]

    const int tid  = threadIdx.x;
    const int lane = tid & 63;
    const int wv   = tid >> 6;
    const int tile = blockIdx.y;
    const int by   = (tile / NTW) * TS;
    const int bx   = (tile % NTW) * TS;
    const int rtA  = blockIdx.x * 2;
    const int quad = lane >> 4;
    const int col  = lane & 15;
    const int ycol = col & 3;           // cols 4..15 read dup data; D cols 4..15 unused

    const bf16x8* FHt = Fhi + tile * F_UNITS_PER_TILE;
    const float*  Sqt = SqK + tile * NPIX;

    // stage Y = [y0,y1,y2,1] as f16 hi + f16 residual (value error ~2^-22)
    for (int idx = tid; idx < 4096; idx += 256) {
        int c = idx >> 10, m = idx & 1023;
        float v = 1.0f;
        if (c < 3) v = img[(c * IMH + by + (m >> 5)) * IMW + bx + (m & 31)];
        __fp16 h = (__fp16)v;
        Yhi[c][m] = h;
        Ylo[c][m] = (__fp16)(v - (float)h);
    }

    // block's n-features, pinned (B operand of the Gram MFMA)
    bf16x8 bN[2][3];
    #pragma unroll
    for (int t = 0; t < 2; ++t)
        #pragma unroll
        for (int ks = 0; ks < 3; ++ks)
            bN[t][ks] = FHt[((rtA + t) * 3 + ks) * 64 + lane];
    asm volatile(""
        : "+v"(bN[0][0]), "+v"(bN[0][1]), "+v"(bN[0][2]),
          "+v"(bN[1][0]), "+v"(bN[1][1]), "+v"(bN[1][2]));

    float snK[2];
    #pragma unroll
    for (int t = 0; t < 2; ++t)
        snK[t] = Sqt[(rtA + t) * 16 + col];

    f32x4 Dpv0 = {0.f, 0.f, 0.f, 0.f};
    f32x4 Dpv1 = {0.f, 0.f, 0.f, 0.f};

    __syncthreads();

    #pragma unroll 2
    for (int it = 0; it < 16; ++it) {
        const int mt = wv * 16 + it;
        bf16x8 aF[3];
        #pragma unroll
        for (int ks = 0; ks < 3; ++ks)
            aF[ks] = FHt[(mt * 3 + ks) * 64 + lane];
        const f32x4 sqm = *(const f32x4*)&Sqt[mt * 16 + quad * 4];
        const int yb = mt * 16 + quad * 4;
        const f16x4 bhi = *(const f16x4*)&Yhi[ycol][yb];
        const f16x4 blo = *(const f16x4*)&Ylo[ycol][yb];

        f32x4 C0 = {0.f, 0.f, 0.f, 0.f};
        f32x4 C1 = {0.f, 0.f, 0.f, 0.f};
        #pragma unroll
        for (int ks = 0; ks < 3; ++ks) {   // A = m-feats, B = n-feats -> row=m,col=n
            C0 = __builtin_amdgcn_mfma_f32_16x16x32_bf16(aF[ks], bN[0][ks], C0, 0, 0, 0);
            C1 = __builtin_amdgcn_mfma_f32_16x16x32_bf16(aF[ks], bN[1][ks], C1, 0, 0, 0);
        }

        #pragma unroll
        for (int t = 0; t < 2; ++t) {
            f32x4 C = t ? C1 : C0;
            float d[4];
            #pragma unroll
            for (int i = 0; i < 4; ++i) {
                float s2 = fmaxf(fmaf(-2.0f * K2LOG2E, C[i], sqm[i] + snK[t]), 0.f);
                d[i] = __builtin_amdgcn_exp2f(-__builtin_amdgcn_sqrtf(s2));
            }
            if (mt == rtA + t) {            // wave-uniform: diag fragment only
                #pragma unroll
                for (int i = 0; i < 4; ++i)
                    if (quad * 4 + i == col) d[i] = 0.f;
            }
            f16x2 p0 = __builtin_amdgcn_cvt_pkrtz(d[0], d[1]);
            f16x2 p1 = __builtin_amdgcn_cvt_pkrtz(d[2], d[3]);
            f16x4 wp = __builtin_shufflevector(p0, p1, 0, 1, 2, 3);
            if (t == 0) {
                Dpv0 = __builtin_amdgcn_mfma_f32_16x16x16f16(wp, bhi, Dpv0, 0, 0, 0);
                Dpv0 = __builtin_amdgcn_mfma_f32_16x16x16f16(wp, blo, Dpv0, 0, 0, 0);
            } else {
                Dpv1 = __builtin_amdgcn_mfma_f32_16x16x16f16(wp, bhi, Dpv1, 0, 0, 0);
                Dpv1 = __builtin_amdgcn_mfma_f32_16x16x16f16(wp, blo, Dpv1, 0, 0, 0);
            }
        }
    }

    // cross-wave reduce: Dpv row = n-local (4q+i), col = channel (0..3 valid)
    if (col < 4) {
        #pragma unroll
        for (int i = 0; i < 4; ++i) {
            red[wv][0][quad * 4 + i][col] = Dpv0[i];
            red[wv][1][quad * 4 + i][col] = Dpv1[i];
        }
    }
    __syncthreads();

    if (tid < 128) {
        int n = tid >> 2, c = tid & 3;
        int t = n >> 4, r = n & 15;
        float s = red[0][t][r][c] + red[1][t][r][c]
                + red[2][t][r][c] + red[3][t][r][c];
        float rs = __shfl(s, (tid & 63) | 3, 64);   // c==3 slot = rowsum
        if (c < 3) {
            int nn = rtA * 16 + n;
            int gy = by + (nn >> 5), gx = bx + (nn & 31);
            out[(c * IMH + gy) * IMW + gx] = s * (1.0f / rs);
        }
    }
}

extern "C" void kernel_launch(void* const* d_in, const int* in_sizes, int n_in,
                              void* d_out, int out_size, void* d_ws, size_t ws_size,
                              hipStream_t stream) {
    const float* img = (const float*)d_in[0];
    float* out = (float*)d_out;
    char* ws = (char*)d_ws;
    u16x8* Fhi = (u16x8*)ws;
    float* Sq  = (float*)(ws + SQ_OFF);

    dim3 fgrid(16, NTILE);
    nlm_feat_kernel<<<fgrid, 256, 0, stream>>>(img, Fhi, Sq);
    dim3 grid(32, NTILE);
    nlm_gemm_kernel<<<grid, 256, 0, stream>>>(img, (const bf16x8*)Fhi, Sq, out);
}

// Round 3
// 121.717 us; speedup vs baseline: 1.0627x; 1.0627x over previous
//
#include <hip/hip_runtime.h>
#include <math.h>

#define TS   32
#define PT   36
#define NPIX 1024
#define DF   72      // real feature dim
#define KP   96      // padded K: 3 MFMA k-steps of 32
#define IMH  320
#define IMW  320
#define NTW  10
#define NTILE 100

// ws layout offsets unchanged from proven R3..R11
#define F_UNITS_PER_TILE 12288           // 64 rt * 3 ks * 4 c * 16 rows
#define FHI_BYTES (NTILE * F_UNITS_PER_TILE * 16)   // 19,660,800
#define SQ_OFF    (2 * FHI_BYTES)                   // 39,321,600

#define K2LOG2E 2.0813689810056077f      // (log2 e)^2: exp(-sqrt(x)) = exp2(-sqrt(K2*x))

typedef __attribute__((ext_vector_type(8))) short bf16x8;   // MFMA A/B frag
typedef __attribute__((ext_vector_type(8))) unsigned short u16x8;
typedef __attribute__((ext_vector_type(4))) float f32x4;    // MFMA C/D
typedef __attribute__((ext_vector_type(4))) __fp16 f16x4;   // 16x16x16 f16 A/B frag
typedef __attribute__((ext_vector_type(2))) __fp16 f16x2;

// ---------------- kernel A: feature build (RNE bf16) + sqf ----------------
__global__ __launch_bounds__(256)
void nlm_feat_kernel(const float* __restrict__ img,
                     u16x8* __restrict__ Fhi, float* __restrict__ Sq)
{
    __shared__ float Ploc[3][6][36];   // padded rows [2p, 2p+6) of the tile
    __shared__ int   ofsl[KP];
    const int tid  = threadIdx.x;
    const int part = blockIdx.x;    // 0..15
    const int tile = blockIdx.y;
    const int by   = (tile / NTW) * TS;
    const int bx   = (tile % NTW) * TS;
    const float* Pf = &Ploc[0][0][0];

    for (int idx = tid; idx < 3 * 6 * 36; idx += 256) {
        int c   = idx / 216;
        int rem = idx - c * 216;
        int yl  = rem / 36;
        int x   = rem - yl * 36;
        int y   = 2 * part + yl;
        int iy  = min(max(y - 2, 0), TS - 1);
        int ix  = min(max(x - 2, 0), TS - 1);
        Ploc[c][yl][x] = img[(c * IMH + by + iy) * IMW + bx + ix];
    }
    if (tid < KP) {
        int k = tid, v = 0;
        if (k < DF) {
            int c = k / 24, o = k - c * 24;
            int kk = o + (o >= 12);
            int i = kk / 5, j = kk - (kk / 5) * 5;
            v = c * 216 + i * 36 + j;
        }
        ofsl[k] = v;
    }
    __syncthreads();

    if (tid < 64) {
        int m  = part * 64 + tid;
        int my = m >> 5, mx = m & 31;
        int ly0 = my - 2 * part;
        float s = 0.f;
        #pragma unroll
        for (int k = 0; k < 25; ++k) {
            if (k == 12) continue;
            int i = k / 5, j = k - (k / 5) * 5;
            float v0 = Ploc[0][ly0 + i][mx + j];
            float v1 = Ploc[1][ly0 + i][mx + j];
            float v2 = Ploc[2][ly0 + i][mx + j];
            s = fmaf(v0, v0, s); s = fmaf(v1, v1, s); s = fmaf(v2, v2, s);
        }
        Sq[tile * NPIX + m] = s * K2LOG2E;   // pre-scaled
    }

    #pragma unroll
    for (int q = 0; q < 3; ++q) {
        int u    = part * 768 + q * 256 + tid;
        int row  = u & 15;
        int c4   = (u >> 4) & 3;
        int rks  = u >> 6;
        int ks   = rks - (rks / 3) * 3;
        int rt   = rks / 3;
        int r    = rt * 16 + row;
        int lbase = ((r >> 5) - 2 * part) * 36 + (r & 31);
        u16x8 h;
        #pragma unroll
        for (int j = 0; j < 8; ++j) {
            int k = ks * 32 + c4 * 8 + j;
            unsigned short hs = 0;
            if (k < DF) {
                float f = Pf[lbase + ofsl[k]];
                unsigned int uu = __float_as_uint(f);
                hs = (unsigned short)((uu + 0x7fffu + ((uu >> 16) & 1u)) >> 16);
            }
            h[j] = hs;
        }
        Fhi[tile * F_UNITS_PER_TILE + u] = h;
    }
}

// ---------------- kernel B: Gram MFMA + PV-MFMA accumulation --------------
// R12: operand-swapped Gram (row=m,col=n; valid: S symmetric); densities feed
// a K=16 f16 PV MFMA with B=[y0,y1,y2,1] (hi + lo residual) in-layout.
// R13: latency-bound fix — waves_per_eu(4,8) (VGPR=68 allows it; old (2,3)
// cap was for the VGPR-72 spill-prone variant), split hi/lo PV accumulators,
// XCD-swizzled 1-D grid so one tile's 197KB Fhi panel stays in one XCD L2.
__global__ __launch_bounds__(256)
__attribute__((amdgpu_waves_per_eu(4, 8)))
void nlm_gemm_kernel(const float* __restrict__ img,
                     const bf16x8* __restrict__ Fhi,
                     const float* __restrict__ SqK, float* __restrict__ out)
{
    __shared__ __fp16 Yhi[4][1032];   // pitch 1032: banks 0/4/8/12 across c
    __shared__ __fp16 Ylo[4][1032];
    __shared__ float red[4][2][16][4];  // [wave][t][row][c]

    const int tid  = threadIdx.x;
    const int lane = tid & 63;
    const int wv   = tid >> 6;
    // XCD swizzle: block i -> XCD i%8 (round-robin dispatch). Give each XCD a
    // contiguous slab of (tile, rt-pair) work items: w = (i%8)*400 + i/8.
    const int i0   = blockIdx.x;
    const int w    = (i0 & 7) * 400 + (i0 >> 3);
    const int tile = w >> 5;
    const int rtA  = (w & 31) * 2;
    const int by   = (tile / NTW) * TS;
    const int bx   = (tile % NTW) * TS;
    const int quad = lane >> 4;
    const int col  = lane & 15;
    const int ycol = col & 3;           // cols 4..15 read dup data; D cols 4..15 unused

    const bf16x8* FHt = Fhi + tile * F_UNITS_PER_TILE;
    const float*  Sqt = SqK + tile * NPIX;

    // stage Y = [y0,y1,y2,1] as f16 hi + f16 residual (value error ~2^-22)
    for (int idx = tid; idx < 4096; idx += 256) {
        int c = idx >> 10, m = idx & 1023;
        float v = 1.0f;
        if (c < 3) v = img[(c * IMH + by + (m >> 5)) * IMW + bx + (m & 31)];
        __fp16 h = (__fp16)v;
        Yhi[c][m] = h;
        Ylo[c][m] = (__fp16)(v - (float)h);
    }

    // block's n-features, pinned (B operand of the Gram MFMA)
    bf16x8 bN[2][3];
    #pragma unroll
    for (int t = 0; t < 2; ++t)
        #pragma unroll
        for (int ks = 0; ks < 3; ++ks)
            bN[t][ks] = FHt[((rtA + t) * 3 + ks) * 64 + lane];
    asm volatile(""
        : "+v"(bN[0][0]), "+v"(bN[0][1]), "+v"(bN[0][2]),
          "+v"(bN[1][0]), "+v"(bN[1][1]), "+v"(bN[1][2]));

    float snK[2];
    #pragma unroll
    for (int t = 0; t < 2; ++t)
        snK[t] = Sqt[(rtA + t) * 16 + col];

    f32x4 DpvH0 = {0.f, 0.f, 0.f, 0.f};
    f32x4 DpvL0 = {0.f, 0.f, 0.f, 0.f};
    f32x4 DpvH1 = {0.f, 0.f, 0.f, 0.f};
    f32x4 DpvL1 = {0.f, 0.f, 0.f, 0.f};

    __syncthreads();

    #pragma unroll 2
    for (int it = 0; it < 16; ++it) {
        const int mt = wv * 16 + it;
        bf16x8 aF[3];
        #pragma unroll
        for (int ks = 0; ks < 3; ++ks)
            aF[ks] = FHt[(mt * 3 + ks) * 64 + lane];
        const f32x4 sqm = *(const f32x4*)&Sqt[mt * 16 + quad * 4];
        const int yb = mt * 16 + quad * 4;
        const f16x4 bhi = *(const f16x4*)&Yhi[ycol][yb];
        const f16x4 blo = *(const f16x4*)&Ylo[ycol][yb];

        f32x4 C0 = {0.f, 0.f, 0.f, 0.f};
        f32x4 C1 = {0.f, 0.f, 0.f, 0.f};
        #pragma unroll
        for (int ks = 0; ks < 3; ++ks) {   // A = m-feats, B = n-feats -> row=m,col=n
            C0 = __builtin_amdgcn_mfma_f32_16x16x32_bf16(aF[ks], bN[0][ks], C0, 0, 0, 0);
            C1 = __builtin_amdgcn_mfma_f32_16x16x32_bf16(aF[ks], bN[1][ks], C1, 0, 0, 0);
        }

        #pragma unroll
        for (int t = 0; t < 2; ++t) {
            f32x4 C = t ? C1 : C0;
            float d[4];
            #pragma unroll
            for (int i = 0; i < 4; ++i) {
                float s2 = fmaxf(fmaf(-2.0f * K2LOG2E, C[i], sqm[i] + snK[t]), 0.f);
                d[i] = __builtin_amdgcn_exp2f(-__builtin_amdgcn_sqrtf(s2));
            }
            if (mt == rtA + t) {            // wave-uniform: diag fragment only
                #pragma unroll
                for (int i = 0; i < 4; ++i)
                    if (quad * 4 + i == col) d[i] = 0.f;
            }
            f16x2 p0 = __builtin_amdgcn_cvt_pkrtz(d[0], d[1]);
            f16x2 p1 = __builtin_amdgcn_cvt_pkrtz(d[2], d[3]);
            f16x4 wp = __builtin_shufflevector(p0, p1, 0, 1, 2, 3);
            if (t == 0) {
                DpvH0 = __builtin_amdgcn_mfma_f32_16x16x16f16(wp, bhi, DpvH0, 0, 0, 0);
                DpvL0 = __builtin_amdgcn_mfma_f32_16x16x16f16(wp, blo, DpvL0, 0, 0, 0);
            } else {
                DpvH1 = __builtin_amdgcn_mfma_f32_16x16x16f16(wp, bhi, DpvH1, 0, 0, 0);
                DpvL1 = __builtin_amdgcn_mfma_f32_16x16x16f16(wp, blo, DpvL1, 0, 0, 0);
            }
        }
    }

    // cross-wave reduce: Dpv row = n-local (4q+i), col = channel (0..3 valid)
    if (col < 4) {
        #pragma unroll
        for (int i = 0; i < 4; ++i) {
            red[wv][0][quad * 4 + i][col] = DpvH0[i] + DpvL0[i];
            red[wv][1][quad * 4 + i][col] = DpvH1[i] + DpvL1[i];
        }
    }
    __syncthreads();

    if (tid < 128) {
        int n = tid >> 2, c = tid & 3;
        int t = n >> 4, r = n & 15;
        float s = red[0][t][r][c] + red[1][t][r][c]
                + red[2][t][r][c] + red[3][t][r][c];
        float rs = __shfl(s, (tid & 63) | 3, 64);   // c==3 slot = rowsum
        if (c < 3) {
            int nn = rtA * 16 + n;
            int gy = by + (nn >> 5), gx = bx + (nn & 31);
            out[(c * IMH + gy) * IMW + gx] = s * (1.0f / rs);
        }
    }
}

extern "C" void kernel_launch(void* const* d_in, const int* in_sizes, int n_in,
                              void* d_out, int out_size, void* d_ws, size_t ws_size,
                              hipStream_t stream) {
    const float* img = (const float*)d_in[0];
    float* out = (float*)d_out;
    char* ws = (char*)d_ws;
    u16x8* Fhi = (u16x8*)ws;
    float* Sq  = (float*)(ws + SQ_OFF);

    dim3 fgrid(16, NTILE);
    nlm_feat_kernel<<<fgrid, 256, 0, stream>>>(img, Fhi, Sq);
    nlm_gemm_kernel<<<dim3(3200), 256, 0, stream>>>(img, (const bf16x8*)Fhi, Sq, out);
}

// Round 4
// 111.058 us; speedup vs baseline: 1.1647x; 1.0960x over previous
//
#include <hip/hip_runtime.h>
#include <math.h>

#define TS   32
#define PT   36
#define NPIX 1024
#define DF   72      // real feature dim
#define KP   96      // padded K: 3 MFMA k-steps of 32
#define IMH  320
#define IMW  320
#define NTW  10
#define NTILE 100

// ws layout offsets unchanged from proven R3..R11
#define F_UNITS_PER_TILE 12288           // 64 rt * 3 ks * 4 c * 16 rows
#define FHI_BYTES (NTILE * F_UNITS_PER_TILE * 16)   // 19,660,800
#define SQ_OFF    (2 * FHI_BYTES)                   // 39,321,600

#define K2LOG2E 2.0813689810056077f      // (log2 e)^2: exp(-sqrt(x)) = exp2(-sqrt(K2*x))

typedef __attribute__((ext_vector_type(8))) short bf16x8;   // MFMA A/B frag
typedef __attribute__((ext_vector_type(8))) unsigned short u16x8;
typedef __attribute__((ext_vector_type(4))) float f32x4;    // MFMA C/D
typedef __attribute__((ext_vector_type(4))) __fp16 f16x4;   // 16x16x16 f16 A/B frag
typedef __attribute__((ext_vector_type(2))) __fp16 f16x2;

// ---------------- kernel A: feature build (RNE bf16) + sqf ----------------
__global__ __launch_bounds__(256)
void nlm_feat_kernel(const float* __restrict__ img,
                     u16x8* __restrict__ Fhi, float* __restrict__ Sq)
{
    __shared__ float Ploc[3][6][36];   // padded rows [2p, 2p+6) of the tile
    __shared__ int   ofsl[KP];
    const int tid  = threadIdx.x;
    const int part = blockIdx.x;    // 0..15
    const int tile = blockIdx.y;
    const int by   = (tile / NTW) * TS;
    const int bx   = (tile % NTW) * TS;
    const float* Pf = &Ploc[0][0][0];

    for (int idx = tid; idx < 3 * 6 * 36; idx += 256) {
        int c   = idx / 216;
        int rem = idx - c * 216;
        int yl  = rem / 36;
        int x   = rem - yl * 36;
        int y   = 2 * part + yl;
        int iy  = min(max(y - 2, 0), TS - 1);
        int ix  = min(max(x - 2, 0), TS - 1);
        Ploc[c][yl][x] = img[(c * IMH + by + iy) * IMW + bx + ix];
    }
    if (tid < KP) {
        int k = tid, v = 0;
        if (k < DF) {
            int c = k / 24, o = k - c * 24;
            int kk = o + (o >= 12);
            int i = kk / 5, j = kk - (kk / 5) * 5;
            v = c * 216 + i * 36 + j;
        }
        ofsl[k] = v;
    }
    __syncthreads();

    if (tid < 64) {
        int m  = part * 64 + tid;
        int my = m >> 5, mx = m & 31;
        int ly0 = my - 2 * part;
        float s = 0.f;
        #pragma unroll
        for (int k = 0; k < 25; ++k) {
            if (k == 12) continue;
            int i = k / 5, j = k - (k / 5) * 5;
            float v0 = Ploc[0][ly0 + i][mx + j];
            float v1 = Ploc[1][ly0 + i][mx + j];
            float v2 = Ploc[2][ly0 + i][mx + j];
            s = fmaf(v0, v0, s); s = fmaf(v1, v1, s); s = fmaf(v2, v2, s);
        }
        Sq[tile * NPIX + m] = s * K2LOG2E;   // pre-scaled
    }

    #pragma unroll
    for (int q = 0; q < 3; ++q) {
        int u    = part * 768 + q * 256 + tid;
        int row  = u & 15;
        int c4   = (u >> 4) & 3;
        int rks  = u >> 6;
        int ks   = rks - (rks / 3) * 3;
        int rt   = rks / 3;
        int r    = rt * 16 + row;
        int lbase = ((r >> 5) - 2 * part) * 36 + (r & 31);
        u16x8 h;
        #pragma unroll
        for (int j = 0; j < 8; ++j) {
            int k = ks * 32 + c4 * 8 + j;
            unsigned short hs = 0;
            if (k < DF) {
                float f = Pf[lbase + ofsl[k]];
                unsigned int uu = __float_as_uint(f);
                hs = (unsigned short)((uu + 0x7fffu + ((uu >> 16) & 1u)) >> 16);
            }
            h[j] = hs;
        }
        Fhi[tile * F_UNITS_PER_TILE + u] = h;
    }
}

// ---------------- kernel B: Gram MFMA + PV-MFMA accumulation --------------
// R12: operand-swapped Gram (row=m,col=n); densities feed K=16 f16 PV MFMA
//      with B=[y0,y1,y2,1] (hi + lo residual) in A-fragment layout.
// R13: XCD-swizzled 1-D grid (FETCH 84->10.8MB), waves cap lifted.
// R14: latency fix — two-deep register pipeline (named ping-pong buffers,
//      rule #20), next-iter {aF,sqm,bhi,blo} issued before current compute so
//      load->use distance (~270cy compute) covers L2 latency (~250cy).
//      Y staging vectorized float4.
__global__ __launch_bounds__(256)
__attribute__((amdgpu_waves_per_eu(4, 8)))
void nlm_gemm_kernel(const float* __restrict__ img,
                     const bf16x8* __restrict__ Fhi,
                     const float* __restrict__ SqK, float* __restrict__ out)
{
    __shared__ __fp16 Yhi[4][1032];   // pitch 1032: banks 0/4/8/12 across c
    __shared__ __fp16 Ylo[4][1032];
    __shared__ float red[4][2][16][4];  // [wave][t][row][c]

    const int tid  = threadIdx.x;
    const int lane = tid & 63;
    const int wv   = tid >> 6;
    // XCD swizzle: block i -> XCD i%8; each XCD gets a contiguous work slab.
    const int i0   = blockIdx.x;
    const int w    = (i0 & 7) * 400 + (i0 >> 3);
    const int tile = w >> 5;
    const int rtA  = (w & 31) * 2;
    const int by   = (tile / NTW) * TS;
    const int bx   = (tile % NTW) * TS;
    const int quad = lane >> 4;
    const int col  = lane & 15;
    const int ycol = col & 3;           // cols 4..15 dup; D cols 4..15 unused

    const bf16x8* FHt = Fhi + tile * F_UNITS_PER_TILE;
    const float*  Sqt = SqK + tile * NPIX;

    // stage Y = [y0,y1,y2,1] as f16 hi + f16 residual, float4-vectorized
    for (int idx = tid; idx < 1024; idx += 256) {
        int c = idx >> 8, m4 = (idx & 255) << 2;
        f32x4 v = {1.f, 1.f, 1.f, 1.f};
        if (c < 3) v = *(const f32x4*)&img[(c * IMH + by + (m4 >> 5)) * IMW + bx + (m4 & 31)];
        f16x4 h, l;
        #pragma unroll
        for (int j = 0; j < 4; ++j) {
            h[j] = (__fp16)v[j];
            l[j] = (__fp16)(v[j] - (float)h[j]);
        }
        *(f16x4*)&Yhi[c][m4] = h;
        *(f16x4*)&Ylo[c][m4] = l;
    }

    // block's n-features, pinned (B operand of the Gram MFMA)
    bf16x8 bN[2][3];
    #pragma unroll
    for (int t = 0; t < 2; ++t)
        #pragma unroll
        for (int ks = 0; ks < 3; ++ks)
            bN[t][ks] = FHt[((rtA + t) * 3 + ks) * 64 + lane];
    asm volatile(""
        : "+v"(bN[0][0]), "+v"(bN[0][1]), "+v"(bN[0][2]),
          "+v"(bN[1][0]), "+v"(bN[1][1]), "+v"(bN[1][2]));

    float snK[2];
    #pragma unroll
    for (int t = 0; t < 2; ++t)
        snK[t] = Sqt[(rtA + t) * 16 + col];

    f32x4 DpvH0 = {0.f, 0.f, 0.f, 0.f};
    f32x4 DpvL0 = {0.f, 0.f, 0.f, 0.f};
    f32x4 DpvH1 = {0.f, 0.f, 0.f, 0.f};
    f32x4 DpvL1 = {0.f, 0.f, 0.f, 0.f};

    __syncthreads();

    const int mtBase = wv * 16;

    // two-deep ping-pong pipeline: named buffer sets A/B (no runtime indexing)
    bf16x8 aFA0, aFA1, aFA2, aFB0, aFB1, aFB2;
    f32x4 sqA, sqB;
    f16x4 bhiA, bloA, bhiB, bloB;

#define LOADF(mt, a0, a1, a2, sq, bh, bl)                      \
    do {                                                       \
        int _mt = (mt);                                        \
        a0 = FHt[(_mt * 3 + 0) * 64 + lane];                   \
        a1 = FHt[(_mt * 3 + 1) * 64 + lane];                   \
        a2 = FHt[(_mt * 3 + 2) * 64 + lane];                   \
        sq = *(const f32x4*)&Sqt[_mt * 16 + quad * 4];         \
        bh = *(const f16x4*)&Yhi[ycol][_mt * 16 + quad * 4];   \
        bl = *(const f16x4*)&Ylo[ycol][_mt * 16 + quad * 4];   \
    } while (0)

#define COMPUTE(mt, a0, a1, a2, sq, bh, bl)                                          \
    do {                                                                             \
        int _mt = (mt);                                                              \
        f32x4 C0 = {0.f, 0.f, 0.f, 0.f};                                             \
        f32x4 C1 = {0.f, 0.f, 0.f, 0.f};                                             \
        C0 = __builtin_amdgcn_mfma_f32_16x16x32_bf16(a0, bN[0][0], C0, 0, 0, 0);     \
        C1 = __builtin_amdgcn_mfma_f32_16x16x32_bf16(a0, bN[1][0], C1, 0, 0, 0);     \
        C0 = __builtin_amdgcn_mfma_f32_16x16x32_bf16(a1, bN[0][1], C0, 0, 0, 0);     \
        C1 = __builtin_amdgcn_mfma_f32_16x16x32_bf16(a1, bN[1][1], C1, 0, 0, 0);     \
        C0 = __builtin_amdgcn_mfma_f32_16x16x32_bf16(a2, bN[0][2], C0, 0, 0, 0);     \
        C1 = __builtin_amdgcn_mfma_f32_16x16x32_bf16(a2, bN[1][2], C1, 0, 0, 0);     \
        _Pragma("unroll")                                                            \
        for (int t = 0; t < 2; ++t) {                                                \
            f32x4 C = t ? C1 : C0;                                                   \
            float d[4];                                                              \
            _Pragma("unroll")                                                        \
            for (int i = 0; i < 4; ++i) {                                            \
                float s2 = fmaxf(fmaf(-2.0f * K2LOG2E, C[i], sq[i] + snK[t]), 0.f);  \
                d[i] = __builtin_amdgcn_exp2f(-__builtin_amdgcn_sqrtf(s2));          \
            }                                                                        \
            if (_mt == rtA + t) {                                                    \
                _Pragma("unroll")                                                    \
                for (int i = 0; i < 4; ++i)                                          \
                    if (quad * 4 + i == col) d[i] = 0.f;                             \
            }                                                                        \
            f16x2 p0 = __builtin_amdgcn_cvt_pkrtz(d[0], d[1]);                       \
            f16x2 p1 = __builtin_amdgcn_cvt_pkrtz(d[2], d[3]);                       \
            f16x4 wp = __builtin_shufflevector(p0, p1, 0, 1, 2, 3);                  \
            if (t == 0) {                                                            \
                DpvH0 = __builtin_amdgcn_mfma_f32_16x16x16f16(wp, bh, DpvH0, 0, 0, 0); \
                DpvL0 = __builtin_amdgcn_mfma_f32_16x16x16f16(wp, bl, DpvL0, 0, 0, 0); \
            } else {                                                                 \
                DpvH1 = __builtin_amdgcn_mfma_f32_16x16x16f16(wp, bh, DpvH1, 0, 0, 0); \
                DpvL1 = __builtin_amdgcn_mfma_f32_16x16x16f16(wp, bl, DpvL1, 0, 0, 0); \
            }                                                                        \
        }                                                                            \
    } while (0)

    LOADF(mtBase, aFA0, aFA1, aFA2, sqA, bhiA, bloA);
    #pragma unroll
    for (int it2 = 0; it2 < 8; ++it2) {
        const int mt0 = mtBase + it2 * 2;
        LOADF(mt0 + 1, aFB0, aFB1, aFB2, sqB, bhiB, bloB);
        COMPUTE(mt0, aFA0, aFA1, aFA2, sqA, bhiA, bloA);
        if (it2 < 7)
            LOADF(mt0 + 2, aFA0, aFA1, aFA2, sqA, bhiA, bloA);
        COMPUTE(mt0 + 1, aFB0, aFB1, aFB2, sqB, bhiB, bloB);
    }
#undef LOADF
#undef COMPUTE

    // cross-wave reduce: Dpv row = n-local (4q+i), col = channel (0..3 valid)
    if (col < 4) {
        #pragma unroll
        for (int i = 0; i < 4; ++i) {
            red[wv][0][quad * 4 + i][col] = DpvH0[i] + DpvL0[i];
            red[wv][1][quad * 4 + i][col] = DpvH1[i] + DpvL1[i];
        }
    }
    __syncthreads();

    if (tid < 128) {
        int n = tid >> 2, c = tid & 3;
        int t = n >> 4, r = n & 15;
        float s = red[0][t][r][c] + red[1][t][r][c]
                + red[2][t][r][c] + red[3][t][r][c];
        float rs = __shfl(s, (tid & 63) | 3, 64);   // c==3 slot = rowsum
        if (c < 3) {
            int nn = rtA * 16 + n;
            int gy = by + (nn >> 5), gx = bx + (nn & 31);
            out[(c * IMH + gy) * IMW + gx] = s * (1.0f / rs);
        }
    }
}

extern "C" void kernel_launch(void* const* d_in, const int* in_sizes, int n_in,
                              void* d_out, int out_size, void* d_ws, size_t ws_size,
                              hipStream_t stream) {
    const float* img = (const float*)d_in[0];
    float* out = (float*)d_out;
    char* ws = (char*)d_ws;
    u16x8* Fhi = (u16x8*)ws;
    float* Sq  = (float*)(ws + SQ_OFF);

    dim3 fgrid(16, NTILE);
    nlm_feat_kernel<<<fgrid, 256, 0, stream>>>(img, Fhi, Sq);
    nlm_gemm_kernel<<<dim3(3200), 256, 0, stream>>>(img, (const bf16x8*)Fhi, Sq, out);
}